// Round 6
// baseline (490.358 us; speedup 1.0000x reference)
//
#include <hip/hip_runtime.h>
#include <hip/hip_fp16.h>

// RoI Align 14x14, bilinear, spatial_scale = 0.0625.
// features: (N=2, C=512, H=100, W=152) fp32 NCHW
// rois:     (R=512, 5) fp32
// out:      (R, 512, 14, 14) fp32
//
// v6: explicit-MLP gather.
//   T1: NCHW fp32 -> NHWC fp16 staging (proven).
//   G : lane = 8ch (u32x4, 1KB/wave-request, full 512ch per tap).
//       Named ping-pong prefetch (a/b) keeps >=8 x 1KB loads in flight
//       per wave at all times (compiler-proof: no runtime-indexed register
//       arrays, no barriers). Wave-private LDS tile -> NCHW stores.

#define AH 14
#define AW 14
#define NB (AH * AW)            // 196

constexpr int Nn  = 2;
constexpr int Cc  = 512;
constexpr int Hh  = 100;
constexpr int Ww  = 152;
constexpr int HW  = Hh * Ww;    // 15200

constexpr int TROW = 520;       // LDS tile row stride in floats

typedef float        f32x4 __attribute__((ext_vector_type(4)));
typedef unsigned int u32x4 __attribute__((ext_vector_type(4)));

__device__ __forceinline__ float2 h2f(unsigned int u)
{
    return __half22float2(*reinterpret_cast<const __half2*>(&u));
}

// ---------------------------------------------------------------- T1
__global__ __launch_bounds__(256)
void nchw_to_nhwc_f16(const float* __restrict__ feat, __half* __restrict__ nhwc)
{
    __shared__ float tile[64][65];

    const int n  = blockIdx.z;
    const int s0 = blockIdx.x * 64;
    const int c0 = blockIdx.y * 64;
    const int q  = (threadIdx.x & 15) * 4;
    const int g  = threadIdx.x >> 4;

    const float* A = feat + (size_t)n * Cc * HW;
    __half*      B = nhwc + (size_t)n * HW * Cc;

    if (s0 + q < HW) {
        #pragma unroll
        for (int i = 0; i < 4; ++i) {
            const int cl = g + 16 * i;
            const f32x4 v = __builtin_nontemporal_load(
                (const f32x4*)&A[(size_t)(c0 + cl) * HW + (s0 + q)]);
            tile[cl][q + 0] = v[0];
            tile[cl][q + 1] = v[1];
            tile[cl][q + 2] = v[2];
            tile[cl][q + 3] = v[3];
        }
    }
    __syncthreads();

    const int c8    = (threadIdx.x & 7) * 8;
    const int sbase = threadIdx.x >> 3;
    #pragma unroll
    for (int i = 0; i < 2; ++i) {
        const int sl = sbase + 32 * i;
        if (s0 + sl < HW) {
            __half2 h[4];
            #pragma unroll
            for (int k = 0; k < 4; ++k)
                h[k] = __floats2half2_rn(tile[c8 + 2 * k][sl],
                                         tile[c8 + 2 * k + 1][sl]);
            *(uint4*)(B + (size_t)(s0 + sl) * Cc + c0 + c8) = *(uint4*)h;
        }
    }
}

// ---------------------------------------------------------------- G
// grid (R, 2), 128 threads = 2 waves. stripe = blockIdx.y*2 + wid owns
// bins [stripe*49, stripe*49+49). Lane = 8 channels (full 512 per wave).
__global__ __launch_bounds__(128, 2)
void roi_gather2_f16(const __half* __restrict__ nhwc,
                     const float* __restrict__ rois,
                     float* __restrict__ out)
{
    const int r      = blockIdx.x;
    const int tid    = threadIdx.x;
    const int lane   = tid & 63;
    const int wid    = tid >> 6;                 // 0..1
    const int stripe = blockIdx.y * 2 + wid;     // 0..3
    const int bin0   = stripe * 49;

    __shared__ int4   s_off[NB];                 // tap offsets in u32x4 units
    __shared__ float4 s_w[NB];
    __shared__ int    s_base;                    // batch base in u32x4 units
    __shared__ float  tiles[2][7 * TROW];        // wave-private, 14.6 KB each

    const float* roi = rois + r * 5;
    const float x_start = roi[1] * 0.0625f;
    const float y_start = roi[2] * 0.0625f;
    const float roi_w = fmaxf(roi[3] * 0.0625f - x_start, 0.0f);
    const float roi_h = fmaxf(roi[4] * 0.0625f - y_start, 0.0f);
    const float bin_h = roi_h / (float)(AH - 1);
    const float bin_w = roi_w / (float)(AW - 1);

    if (tid == 0)
        s_base = ((int)roi[0]) * (HW * (Cc / 8));

    for (int i = tid; i < NB; i += 128) {
        const int ph = i / AW;
        const int pw = i - ph * AW;
        float ys = y_start + (float)ph * bin_h;
        float xs = x_start + (float)pw * bin_w;
        ys = fminf(fmaxf(ys, 0.0f), (float)(Hh - 1));
        xs = fminf(fmaxf(xs, 0.0f), (float)(Ww - 1));
        const int y0 = (int)floorf(ys);
        const int x0 = (int)floorf(xs);
        const int y1 = min(y0 + 1, Hh - 1);
        const int x1 = min(x0 + 1, Ww - 1);
        const float wy = ys - (float)y0;
        const float wx = xs - (float)x0;
        // u32x4 units: pixel * (512 halves / 8 halves-per-u32x4) = <<6
        s_off[i] = make_int4((y0 * Ww + x0) << 6, (y0 * Ww + x1) << 6,
                             (y1 * Ww + x0) << 6, (y1 * Ww + x1) << 6);
        s_w[i]   = make_float4((1.0f - wy) * (1.0f - wx),
                               (1.0f - wy) * wx,
                               wy * (1.0f - wx),
                               wy * wx);
    }
    __syncthreads();   // only block-wide barrier

    const u32x4* __restrict__ fb = (const u32x4*)nhwc + s_base + lane;
    float* __restrict__ outr = out + (size_t)r * (Cc * NB);
    float* tile = tiles[wid];

    u32x4  a0, a1, a2, a3, b0, b1, b2, b3;
    float4 wa, wb;

#define LOADS(P0, P1, P2, P3, W, bin)                        \
    {   const int4 o = s_off[bin]; W = s_w[bin];             \
        P0 = __builtin_nontemporal_load(fb + o.x);           \
        P1 = __builtin_nontemporal_load(fb + o.y);           \
        P2 = __builtin_nontemporal_load(fb + o.z);           \
        P3 = __builtin_nontemporal_load(fb + o.w);  }

#define COMPUTE(P0, P1, P2, P3, W, row)                                   \
    {   f32x4 lo, hi;                                                     \
        { const float2 pa = h2f(P0[0]), pb = h2f(P1[0]),                  \
                       pc = h2f(P2[0]), pd = h2f(P3[0]);                  \
          lo[0] = W.x*pa.x + W.y*pb.x + W.z*pc.x + W.w*pd.x;              \
          lo[1] = W.x*pa.y + W.y*pb.y + W.z*pc.y + W.w*pd.y; }            \
        { const float2 pa = h2f(P0[1]), pb = h2f(P1[1]),                  \
                       pc = h2f(P2[1]), pd = h2f(P3[1]);                  \
          lo[2] = W.x*pa.x + W.y*pb.x + W.z*pc.x + W.w*pd.x;              \
          lo[3] = W.x*pa.y + W.y*pb.y + W.z*pc.y + W.w*pd.y; }            \
        { const float2 pa = h2f(P0[2]), pb = h2f(P1[2]),                  \
                       pc = h2f(P2[2]), pd = h2f(P3[2]);                  \
          hi[0] = W.x*pa.x + W.y*pb.x + W.z*pc.x + W.w*pd.x;              \
          hi[1] = W.x*pa.y + W.y*pb.y + W.z*pc.y + W.w*pd.y; }            \
        { const float2 pa = h2f(P0[3]), pb = h2f(P1[3]),                  \
                       pc = h2f(P2[3]), pd = h2f(P3[3]);                  \
          hi[2] = W.x*pa.x + W.y*pb.x + W.z*pc.x + W.w*pd.x;              \
          hi[3] = W.x*pa.y + W.y*pb.y + W.z*pc.y + W.w*pd.y; }            \
        *(f32x4*)&tile[(row) * TROW + 8 * lane]     = lo;                 \
        *(f32x4*)&tile[(row) * TROW + 8 * lane + 4] = hi;  }

#define READBACK(cb)                                         \
    {   _Pragma("unroll")                                    \
        for (int k = 0; k < 8; ++k) {                        \
            const int ch = 8 * lane + k;                     \
            float* op = outr + (size_t)ch * NB + bin0 + (cb);\
            _Pragma("unroll")                                \
            for (int b7 = 0; b7 < 7; ++b7)                   \
                op[b7] = tile[b7 * TROW + ch];               \
        }  }

    LOADS(a0, a1, a2, a3, wa, bin0 + 0);
    LOADS(b0, b1, b2, b3, wb, bin0 + 1);

    int row = 0, cbase = 0;
    for (int i = 0; i < 24; ++i) {
        const int j = 2 * i;
        COMPUTE(a0, a1, a2, a3, wa, row);
        LOADS(a0, a1, a2, a3, wa, bin0 + j + 2);         // j+2 <= 48 always
        if (row == 6) { READBACK(cbase); row = 0; cbase += 7; } else ++row;
        COMPUTE(b0, b1, b2, b3, wb, row);
        if (j + 3 <= 48)
            LOADS(b0, b1, b2, b3, wb, bin0 + j + 3);
        if (row == 6) { READBACK(cbase); row = 0; cbase += 7; } else ++row;
    }
    // tail: bin 48 sits in the a-registers, lands in row 6 of chunk 6
    COMPUTE(a0, a1, a2, a3, wa, row);
    READBACK(cbase);

#undef LOADS
#undef COMPUTE
#undef READBACK
}

// ---------------------------------------------------------------- fallback
__global__ __launch_bounds__(256)
void roi_align_nchw(const float* __restrict__ feat,
                    const float* __restrict__ rois,
                    float* __restrict__ out)
{
    const int r  = blockIdx.x;
    const int c0 = blockIdx.y * 128;

    __shared__ int4   s_off[NB];
    __shared__ float4 s_w[NB];
    __shared__ int    s_base;

    const float* roi = rois + r * 5;
    const float x_start = roi[1] * 0.0625f;
    const float y_start = roi[2] * 0.0625f;
    const float roi_w = fmaxf(roi[3] * 0.0625f - x_start, 0.0f);
    const float roi_h = fmaxf(roi[4] * 0.0625f - y_start, 0.0f);
    const float bin_h = roi_h / (float)(AH - 1);
    const float bin_w = roi_w / (float)(AW - 1);

    if (threadIdx.x == 0)
        s_base = ((int)roi[0]) * (Cc * HW);

    for (int i = threadIdx.x; i < NB; i += blockDim.x) {
        const int ph = i / AW;
        const int pw = i - ph * AW;
        float ys = y_start + (float)ph * bin_h;
        float xs = x_start + (float)pw * bin_w;
        ys = fminf(fmaxf(ys, 0.0f), (float)(Hh - 1));
        xs = fminf(fmaxf(xs, 0.0f), (float)(Ww - 1));
        const int y0 = (int)floorf(ys);
        const int x0 = (int)floorf(xs);
        const int y1 = min(y0 + 1, Hh - 1);
        const int x1 = min(x0 + 1, Ww - 1);
        const float wy = ys - (float)y0;
        const float wx = xs - (float)x0;
        s_off[i] = make_int4(y0 * Ww + x0, y0 * Ww + x1,
                             y1 * Ww + x0, y1 * Ww + x1);
        s_w[i]   = make_float4((1.0f - wy) * (1.0f - wx),
                               (1.0f - wy) * wx,
                               wy * (1.0f - wx),
                               wy * wx);
    }
    __syncthreads();

    const int base = s_base;
    float* __restrict__ outr = out + (size_t)r * (Cc * NB);
    const int jend = (c0 + 128) * NB;
    for (int j = c0 * NB + (int)threadIdx.x * 4; j < jend; j += 256 * 4) {
        const int c   = j / NB;
        const int bin = j - c * NB;
        const float* f = feat + base + c * HW;
        float4 v;
        {
            const int4 o = s_off[bin];     const float4 w = s_w[bin];
            v.x = w.x*f[o.x] + w.y*f[o.y] + w.z*f[o.z] + w.w*f[o.w];
        }
        {
            const int4 o = s_off[bin + 1]; const float4 w = s_w[bin + 1];
            v.y = w.x*f[o.x] + w.y*f[o.y] + w.z*f[o.z] + w.w*f[o.w];
        }
        {
            const int4 o = s_off[bin + 2]; const float4 w = s_w[bin + 2];
            v.z = w.x*f[o.x] + w.y*f[o.y] + w.z*f[o.z] + w.w*f[o.w];
        }
        {
            const int4 o = s_off[bin + 3]; const float4 w = s_w[bin + 3];
            v.w = w.x*f[o.x] + w.y*f[o.y] + w.z*f[o.z] + w.w*f[o.w];
        }
        *(float4*)(outr + j) = v;
    }
}

extern "C" void kernel_launch(void* const* d_in, const int* in_sizes, int n_in,
                              void* d_out, int out_size, void* d_ws, size_t ws_size,
                              hipStream_t stream)
{
    const float* feat = (const float*)d_in[0];
    const float* rois = (const float*)d_in[1];
    float*       out  = (float*)d_out;
    const int R = in_sizes[1] / 5;                       // 512

    const size_t need = (size_t)Nn * HW * Cc * sizeof(__half);  // 31.1 MB
    if (ws_size >= need) {
        __half* nhwc = (__half*)d_ws;
        dim3 tg((HW + 63) / 64, Cc / 64, Nn);            // (238, 8, 2)
        nchw_to_nhwc_f16<<<tg, 256, 0, stream>>>(feat, nhwc);
        roi_gather2_f16<<<dim3(R, 2), 128, 0, stream>>>(nhwc, rois, out);
    } else {
        dim3 grid(R, Cc / 128);
        roi_align_nchw<<<grid, 256, 0, stream>>>(feat, rois, out);
    }
}

// Round 7
// 424.103 us; speedup vs baseline: 1.1562x; 1.1562x over previous
//
#include <hip/hip_runtime.h>
#include <hip/hip_fp16.h>

// RoI Align 14x14, bilinear, spatial_scale = 0.0625.
// features: (N=2, C=512, H=100, W=152) fp32 NCHW
// rois:     (R=512, 5) fp32
// out:      (R, 512, 14, 14) fp32
//
// v7: v3 structure + XCD-aware roi bucketing.
//   T1: NCHW fp32 -> NHWC fp16 staging.
//   P : bucket rois by (batch, y-quartile) -> permutation with bucket k at
//       positions == k (mod 8), so each XCD's resident blocks share a
//       ~3.9MB feature band that fits its private 4MB L2.
//   G : v3's gather (lane=4ch fp16, LDS transpose, nontemporal out stores),
//       indexed through the permutation.

#define AH 14
#define AW 14
#define NB (AH * AW)            // 196

constexpr int Nn  = 2;
constexpr int Cc  = 512;
constexpr int Hh  = 100;
constexpr int Ww  = 152;
constexpr int HW  = Hh * Ww;    // 15200

constexpr int CPB  = 256;       // channels per block (64 lanes x 4 ch)
constexpr int BPP  = 28;        // bins per pass
constexpr int NPASS = NB / BPP; // 7
constexpr int TSF  = 256;       // tile row stride in floats

typedef float f32x4 __attribute__((ext_vector_type(4)));

// ---------------------------------------------------------------- T1
__global__ __launch_bounds__(256)
void nchw_to_nhwc_f16(const float* __restrict__ feat, __half* __restrict__ nhwc)
{
    __shared__ float tile[64][65];

    const int n  = blockIdx.z;
    const int s0 = blockIdx.x * 64;
    const int c0 = blockIdx.y * 64;
    const int q  = (threadIdx.x & 15) * 4;
    const int g  = threadIdx.x >> 4;

    const float* A = feat + (size_t)n * Cc * HW;
    __half*      B = nhwc + (size_t)n * HW * Cc;

    if (s0 + q < HW) {
        #pragma unroll
        for (int i = 0; i < 4; ++i) {
            const int cl = g + 16 * i;
            const f32x4 v = __builtin_nontemporal_load(
                (const f32x4*)&A[(size_t)(c0 + cl) * HW + (s0 + q)]);
            tile[cl][q + 0] = v[0];
            tile[cl][q + 1] = v[1];
            tile[cl][q + 2] = v[2];
            tile[cl][q + 3] = v[3];
        }
    }
    __syncthreads();

    const int c8    = (threadIdx.x & 7) * 8;
    const int sbase = threadIdx.x >> 3;
    #pragma unroll
    for (int i = 0; i < 2; ++i) {
        const int sl = sbase + 32 * i;
        if (s0 + sl < HW) {
            __half2 h[4];
            #pragma unroll
            for (int k = 0; k < 4; ++k)
                h[k] = __floats2half2_rn(tile[c8 + 2 * k][sl],
                                         tile[c8 + 2 * k + 1][sl]);
            *(uint4*)(B + (size_t)(s0 + sl) * Cc + c0 + c8) = *(uint4*)h;
        }
    }
}

// ---------------------------------------------------------------- P
// Single block, >= R threads. Bucket rois by (batch, y-quartile of center).
// Bucket k occupies positions == k (mod 8) (64 strided slots each);
// overflow backfills unused slots serially (thread 0, R=512 -> trivial).
__global__ __launch_bounds__(512)
void bucket_rois(const float* __restrict__ rois, int R, int* __restrict__ perm)
{
    __shared__ int           cnt[8];
    __shared__ int           spillcnt;
    __shared__ short         spill[512];
    __shared__ unsigned char taken[512];

    const int t = threadIdx.x;
    if (t < 8) cnt[t] = 0;
    if (t == 0) spillcnt = 0;
    if (t < R) taken[t] = 0;
    __syncthreads();

    if (t < R) {
        const float* roi = rois + t * 5;
        const int   b  = (int)roi[0];
        const float cy = 0.5f * (roi[2] + roi[4]) * 0.0625f;   // feature y
        int band = (int)(cy * 0.04f);                          // /25 rows
        band = min(max(band, 0), 3);
        const int key  = b * 4 + band;
        const int slot = atomicAdd(&cnt[key], 1);
        if (slot < 64) {
            const int pos = key + 8 * slot;
            perm[pos]  = t;
            taken[pos] = 1;
        } else {
            spill[atomicAdd(&spillcnt, 1)] = (short)t;
        }
    }
    __syncthreads();

    if (t == 0) {
        int s = 0;
        for (int p = 0; p < R && s < spillcnt; ++p)
            if (!taken[p]) perm[p] = spill[s++];
    }
}

// ---------------------------------------------------------------- G (v3 + perm)
__global__ __launch_bounds__(256)
void roi_align_nhwc_f16(const __half* __restrict__ nhwc,
                        const float* __restrict__ rois,
                        const int* __restrict__ perm,
                        float* __restrict__ out)
{
    const int r    = perm[blockIdx.x];
    const int cb0  = blockIdx.y * CPB;        // 0 or 256
    const int tid  = threadIdx.x;
    const int lane = tid & 63;
    const int wid  = tid >> 6;

    __shared__ int4   s_off[NB];              // neighbor offsets in uint2 units
    __shared__ float4 s_w[NB];
    __shared__ int    s_base;                 // batch base in halves
    __shared__ float  tile[BPP * TSF];        // 28.7 KB, rotation-swizzled

    const float* roi = rois + r * 5;
    const float x_start = roi[1] * 0.0625f;
    const float y_start = roi[2] * 0.0625f;
    const float roi_w = fmaxf(roi[3] * 0.0625f - x_start, 0.0f);
    const float roi_h = fmaxf(roi[4] * 0.0625f - y_start, 0.0f);
    const float bin_h = roi_h / (float)(AH - 1);
    const float bin_w = roi_w / (float)(AW - 1);

    if (tid == 0)
        s_base = ((int)roi[0]) * (HW * Cc);

    if (tid < NB) {
        const int ph = tid / AW;
        const int pw = tid - ph * AW;
        float ys = y_start + (float)ph * bin_h;
        float xs = x_start + (float)pw * bin_w;
        ys = fminf(fmaxf(ys, 0.0f), (float)(Hh - 1));
        xs = fminf(fmaxf(xs, 0.0f), (float)(Ww - 1));
        const int y0 = (int)floorf(ys);
        const int x0 = (int)floorf(xs);
        const int y1 = min(y0 + 1, Hh - 1);
        const int x1 = min(x0 + 1, Ww - 1);
        const float wy = ys - (float)y0;
        const float wx = xs - (float)x0;
        s_off[tid] = make_int4((y0 * Ww + x0) << 7, (y0 * Ww + x1) << 7,
                               (y1 * Ww + x0) << 7, (y1 * Ww + x1) << 7);
        s_w[tid]   = make_float4((1.0f - wy) * (1.0f - wx),
                                 (1.0f - wy) * wx,
                                 wy * (1.0f - wx),
                                 wy * wx);
    }
    __syncthreads();

    const uint2* __restrict__ fb = (const uint2*)(nhwc + s_base + cb0) + lane;
    float* __restrict__ outr = out + (size_t)r * (Cc * NB) + (size_t)cb0 * NB;

    for (int pass = 0; pass < NPASS; ++pass) {
        #pragma unroll 2
        for (int bl = wid; bl < BPP; bl += 4) {
            const int bin = pass * BPP + bl;
            const int4   o = s_off[bin];
            const float4 w = s_w[bin];
            const uint2 pa = fb[o.x];
            const uint2 pb = fb[o.y];
            const uint2 pc = fb[o.z];
            const uint2 pd = fb[o.w];
            const float2 a0 = __half22float2(*(const __half2*)&pa.x);
            const float2 a1 = __half22float2(*(const __half2*)&pa.y);
            const float2 b0 = __half22float2(*(const __half2*)&pb.x);
            const float2 b1 = __half22float2(*(const __half2*)&pb.y);
            const float2 c0 = __half22float2(*(const __half2*)&pc.x);
            const float2 c1 = __half22float2(*(const __half2*)&pc.y);
            const float2 d0 = __half22float2(*(const __half2*)&pd.x);
            const float2 d1 = __half22float2(*(const __half2*)&pd.y);
            f32x4 v;
            v[0] = w.x * a0.x + w.y * b0.x + w.z * c0.x + w.w * d0.x;
            v[1] = w.x * a0.y + w.y * b0.y + w.z * c0.y + w.w * d0.y;
            v[2] = w.x * a1.x + w.y * b1.x + w.z * c1.x + w.w * d1.x;
            v[3] = w.x * a1.y + w.y * b1.y + w.z * c1.y + w.w * d1.y;
            const int slot = (lane + (bl >> 2)) & 63;
            *(f32x4*)&tile[bl * TSF + slot * 4] = v;
        }
        __syncthreads();
        #pragma unroll
        for (int k = 0; k < 7; ++k) {
            const int fidx = k * 256 + tid;             // 0..1791
            const int cl   = fidx / 7;                  // channel 0..255
            const int rem  = fidx - cl * 7;             // bin quad 0..6
            const int slot = ((cl >> 2) + rem) & 63;    // matches write swizzle
            const int e    = cl & 3;
            f32x4 v;
            v[0] = tile[(rem * 4 + 0) * TSF + slot * 4 + e];
            v[1] = tile[(rem * 4 + 1) * TSF + slot * 4 + e];
            v[2] = tile[(rem * 4 + 2) * TSF + slot * 4 + e];
            v[3] = tile[(rem * 4 + 3) * TSF + slot * 4 + e];
            __builtin_nontemporal_store(v,
                (f32x4*)&outr[cl * NB + pass * BPP + rem * 4]);
        }
        __syncthreads();
    }
}

// ---------------------------------------------------------------- fallback
__global__ __launch_bounds__(256)
void roi_align_nchw(const float* __restrict__ feat,
                    const float* __restrict__ rois,
                    float* __restrict__ out)
{
    const int r  = blockIdx.x;
    const int c0 = blockIdx.y * 128;

    __shared__ int4   s_off[NB];
    __shared__ float4 s_w[NB];
    __shared__ int    s_base;

    const float* roi = rois + r * 5;
    const float x_start = roi[1] * 0.0625f;
    const float y_start = roi[2] * 0.0625f;
    const float roi_w = fmaxf(roi[3] * 0.0625f - x_start, 0.0f);
    const float roi_h = fmaxf(roi[4] * 0.0625f - y_start, 0.0f);
    const float bin_h = roi_h / (float)(AH - 1);
    const float bin_w = roi_w / (float)(AW - 1);

    if (threadIdx.x == 0)
        s_base = ((int)roi[0]) * (Cc * HW);

    for (int i = threadIdx.x; i < NB; i += blockDim.x) {
        const int ph = i / AW;
        const int pw = i - ph * AW;
        float ys = y_start + (float)ph * bin_h;
        float xs = x_start + (float)pw * bin_w;
        ys = fminf(fmaxf(ys, 0.0f), (float)(Hh - 1));
        xs = fminf(fmaxf(xs, 0.0f), (float)(Ww - 1));
        const int y0 = (int)floorf(ys);
        const int x0 = (int)floorf(xs);
        const int y1 = min(y0 + 1, Hh - 1);
        const int x1 = min(x0 + 1, Ww - 1);
        const float wy = ys - (float)y0;
        const float wx = xs - (float)x0;
        s_off[i] = make_int4(y0 * Ww + x0, y0 * Ww + x1,
                             y1 * Ww + x0, y1 * Ww + x1);
        s_w[i]   = make_float4((1.0f - wy) * (1.0f - wx),
                               (1.0f - wy) * wx,
                               wy * (1.0f - wx),
                               wy * wx);
    }
    __syncthreads();

    const int base = s_base;
    float* __restrict__ outr = out + (size_t)r * (Cc * NB);
    const int jend = (c0 + 128) * NB;
    for (int j = c0 * NB + (int)threadIdx.x * 4; j < jend; j += 256 * 4) {
        const int c   = j / NB;
        const int bin = j - c * NB;
        const float* f = feat + base + c * HW;
        float4 v;
        {
            const int4 o = s_off[bin];     const float4 w = s_w[bin];
            v.x = w.x*f[o.x] + w.y*f[o.y] + w.z*f[o.z] + w.w*f[o.w];
        }
        {
            const int4 o = s_off[bin + 1]; const float4 w = s_w[bin + 1];
            v.y = w.x*f[o.x] + w.y*f[o.y] + w.z*f[o.z] + w.w*f[o.w];
        }
        {
            const int4 o = s_off[bin + 2]; const float4 w = s_w[bin + 2];
            v.z = w.x*f[o.x] + w.y*f[o.y] + w.z*f[o.z] + w.w*f[o.w];
        }
        {
            const int4 o = s_off[bin + 3]; const float4 w = s_w[bin + 3];
            v.w = w.x*f[o.x] + w.y*f[o.y] + w.z*f[o.z] + w.w*f[o.w];
        }
        *(float4*)(outr + j) = v;
    }
}

extern "C" void kernel_launch(void* const* d_in, const int* in_sizes, int n_in,
                              void* d_out, int out_size, void* d_ws, size_t ws_size,
                              hipStream_t stream)
{
    const float* feat = (const float*)d_in[0];
    const float* rois = (const float*)d_in[1];
    float*       out  = (float*)d_out;
    const int R = in_sizes[1] / 5;                       // 512

    const size_t nhwc_bytes = (size_t)Nn * HW * Cc * sizeof(__half); // 31.1 MB
    const size_t perm_off   = (size_t)32 << 20;                      // 32 MB
    const size_t need       = perm_off + (size_t)R * sizeof(int);

    if (ws_size >= need && R <= 512) {
        __half* nhwc = (__half*)d_ws;
        int*    perm = (int*)((char*)d_ws + perm_off);
        dim3 tg((HW + 63) / 64, Cc / 64, Nn);            // (238, 8, 2)
        nchw_to_nhwc_f16<<<tg, 256, 0, stream>>>(feat, nhwc);
        bucket_rois<<<1, 512, 0, stream>>>(rois, R, perm);
        dim3 mg(R, Cc / CPB);                            // (512, 2)
        roi_align_nhwc_f16<<<mg, 256, 0, stream>>>(nhwc, rois, perm, out);
    } else if (ws_size >= nhwc_bytes) {
        // no perm space: identity behavior via fallback path
        dim3 grid(R, Cc / 128);
        roi_align_nchw<<<grid, 256, 0, stream>>>(feat, rois, out);
    } else {
        dim3 grid(R, Cc / 128);
        roi_align_nchw<<<grid, 256, 0, stream>>>(feat, rois, out);
    }
}

// Round 8
// 387.656 us; speedup vs baseline: 1.2649x; 1.0940x over previous
//
#include <hip/hip_runtime.h>
#include <hip/hip_fp16.h>

// RoI Align 14x14, bilinear, spatial_scale = 0.0625.
// features: (N=2, C=512, H=100, W=152) fp32 NCHW
// rois:     (R=512, 5) fp32
// out:      (R, 512, 14, 14) fp32
//
// v8: streaming row-staged gather.
//   T1: NCHW fp32 -> NHWC fp16 staging (proven).
//   G : per (roi, ch-half, bin-row): stage the 2 needed feature rows
//       (x-span <= 29 px, contiguous 512B runs) into LDS via
//       global_load_lds (16B/lane). All bilinear taps then read LDS.
//       Output transpose via v3's verified swizzled tile + NT stores.

#define AH 14
#define AW 14
#define NB (AH * AW)            // 196

constexpr int Nn  = 2;
constexpr int Cc  = 512;
constexpr int Hh  = 100;
constexpr int Ww  = 152;
constexpr int HW  = Hh * Ww;    // 15200

constexpr int CPB = 256;        // channels per block (half)
constexpr int SP  = 32;         // padded px span per staged row
constexpr int TSF = 256;        // tile row stride in floats (swizzled)

typedef float f32x4 __attribute__((ext_vector_type(4)));

// ---------------------------------------------------------------- T1
__global__ __launch_bounds__(256)
void nchw_to_nhwc_f16(const float* __restrict__ feat, __half* __restrict__ nhwc)
{
    __shared__ float tile[64][65];

    const int n  = blockIdx.z;
    const int s0 = blockIdx.x * 64;
    const int c0 = blockIdx.y * 64;
    const int q  = (threadIdx.x & 15) * 4;
    const int g  = threadIdx.x >> 4;

    const float* A = feat + (size_t)n * Cc * HW;
    __half*      B = nhwc + (size_t)n * HW * Cc;

    if (s0 + q < HW) {
        #pragma unroll
        for (int i = 0; i < 4; ++i) {
            const int cl = g + 16 * i;
            const f32x4 v = __builtin_nontemporal_load(
                (const f32x4*)&A[(size_t)(c0 + cl) * HW + (s0 + q)]);
            tile[cl][q + 0] = v[0];
            tile[cl][q + 1] = v[1];
            tile[cl][q + 2] = v[2];
            tile[cl][q + 3] = v[3];
        }
    }
    __syncthreads();

    const int c8    = (threadIdx.x & 7) * 8;
    const int sbase = threadIdx.x >> 3;
    #pragma unroll
    for (int i = 0; i < 2; ++i) {
        const int sl = sbase + 32 * i;
        if (s0 + sl < HW) {
            __half2 h[4];
            #pragma unroll
            for (int k = 0; k < 4; ++k)
                h[k] = __floats2half2_rn(tile[c8 + 2 * k][sl],
                                         tile[c8 + 2 * k + 1][sl]);
            *(uint4*)(B + (size_t)(s0 + sl) * Cc + c0 + c8) = *(uint4*)h;
        }
    }
}

// ---------------------------------------------------------------- G
// grid (R, 2): block = (roi, 256-ch half). 256 threads = 4 waves.
__global__ __launch_bounds__(256)
void roi_align_staged(const __half* __restrict__ nhwc,
                      const float* __restrict__ rois,
                      float* __restrict__ out)
{
    const int r    = blockIdx.x;
    const int cb0  = blockIdx.y * CPB;        // 0 or 256
    const int tid  = threadIdx.x;
    const int lane = tid & 63;
    const int wid  = tid >> 6;

    __shared__ __half stage[2][SP * 256];     // 2 rows x 32 px x 512B = 32 KB
    __shared__ float  tile[28 * TSF];         // 28 KB, rotation-swizzled
    __shared__ int    s_y0[AH], s_y1[AH];
    __shared__ float  s_wy[AH];
    __shared__ int    s_x0[AW], s_x1[AW];     // absolute px
    __shared__ float  s_wx[AW];
    __shared__ int    s_base, s_xlo, s_nst;

    const float* roi = rois + r * 5;
    const float x_start = roi[1] * 0.0625f;
    const float y_start = roi[2] * 0.0625f;
    const float roi_w = fmaxf(roi[3] * 0.0625f - x_start, 0.0f);
    const float roi_h = fmaxf(roi[4] * 0.0625f - y_start, 0.0f);
    const float bin_h = roi_h / (float)(AH - 1);
    const float bin_w = roi_w / (float)(AW - 1);

    if (tid == 0) {
        s_base = ((int)roi[0]) * (HW * Cc);
        const float xs0 = fminf(fmaxf(x_start, 0.0f), (float)(Ww - 1));
        const float xsE = fminf(fmaxf(x_start + 13.0f * bin_w, 0.0f),
                                (float)(Ww - 1));
        const int xlo = (int)floorf(xs0);
        const int xhi = min((int)floorf(xsE) + 1, Ww - 1);
        s_xlo = xlo;
        s_nst = (min(xhi - xlo + 1, SP) + 1) >> 1;    // px-pairs per row
    }
    if (tid < AW) {
        const float xs = fminf(fmaxf(x_start + (float)tid * bin_w, 0.0f),
                               (float)(Ww - 1));
        const int x0 = (int)floorf(xs);
        s_x0[tid] = x0;
        s_x1[tid] = min(x0 + 1, Ww - 1);
        s_wx[tid] = xs - (float)x0;
    }
    if (tid >= 64 && tid < 64 + AH) {
        const int ph = tid - 64;
        const float ys = fminf(fmaxf(y_start + (float)ph * bin_h, 0.0f),
                               (float)(Hh - 1));
        const int y0 = (int)floorf(ys);
        s_y0[ph] = y0;
        s_y1[ph] = min(y0 + 1, Hh - 1);
        s_wy[ph] = ys - (float)y0;
    }
    __syncthreads();

    const int base_ = s_base;
    const int xlo_  = s_xlo;
    const int nst_  = s_nst;
    float* __restrict__ outr = out + (size_t)r * (Cc * NB) + (size_t)cb0 * NB;

    for (int pass = 0; pass < 7; ++pass) {
        for (int rr = 0; rr < 2; ++rr) {
            const int ph = pass * 2 + rr;
            const int ya = s_y0[ph];
            const int yb = s_y1[ph];

            // ---- stage 2 feature rows (contiguous runs, direct-to-LDS)
            for (int i = wid; i < 2 * nst_; i += 4) {
                const int rsel = (i >= nst_) ? 1 : 0;
                const int ii   = rsel ? (i - nst_) : i;
                const int y    = rsel ? yb : ya;
                const int x    = min(xlo_ + 2 * ii + (lane >> 5), Ww - 1);
                const __half* src = nhwc + base_
                                  + ((y * Ww + x) * Cc + cb0)
                                  + (lane & 31) * 8;
                __builtin_amdgcn_global_load_lds(
                    (const __attribute__((address_space(1))) unsigned int*)src,
                    (__attribute__((address_space(3))) unsigned int*)
                        &stage[rsel][ii * 512],
                    16, 0, 0);
            }
            __syncthreads();   // drains vmcnt -> staged data visible

            // ---- taps from LDS, compute, swizzled tile write
            const float wy = s_wy[ph];
            for (int pw = wid; pw < AW; pw += 4) {
                const int p0 = s_x0[pw] - xlo_;
                const int p1 = s_x1[pw] - xlo_;
                const float wx  = s_wx[pw];
                const float w00 = (1.0f - wy) * (1.0f - wx);
                const float w01 = (1.0f - wy) * wx;
                const float w10 = wy * (1.0f - wx);
                const float w11 = wy * wx;

                const uint2 A = *(const uint2*)&stage[0][p0 * 256 + lane * 4];
                const uint2 B = *(const uint2*)&stage[0][p1 * 256 + lane * 4];
                const uint2 C = *(const uint2*)&stage[1][p0 * 256 + lane * 4];
                const uint2 D = *(const uint2*)&stage[1][p1 * 256 + lane * 4];
                const float2 a0 = __half22float2(*(const __half2*)&A.x);
                const float2 a1 = __half22float2(*(const __half2*)&A.y);
                const float2 b0 = __half22float2(*(const __half2*)&B.x);
                const float2 b1 = __half22float2(*(const __half2*)&B.y);
                const float2 c0 = __half22float2(*(const __half2*)&C.x);
                const float2 c1 = __half22float2(*(const __half2*)&C.y);
                const float2 d0 = __half22float2(*(const __half2*)&D.x);
                const float2 d1 = __half22float2(*(const __half2*)&D.y);

                f32x4 v;
                v[0] = w00 * a0.x + w01 * b0.x + w10 * c0.x + w11 * d0.x;
                v[1] = w00 * a0.y + w01 * b0.y + w10 * c0.y + w11 * d0.y;
                v[2] = w00 * a1.x + w01 * b1.x + w10 * c1.x + w11 * d1.x;
                v[3] = w00 * a1.y + w01 * b1.y + w10 * c1.y + w11 * d1.y;

                const int bl   = rr * AW + pw;            // 0..27
                const int slot = (lane + (bl >> 2)) & 63; // v3 swizzle
                *(f32x4*)&tile[bl * TSF + slot * 4] = v;
            }
            __syncthreads();   // protect stage (re-staged next rr) + tile
        }

        // ---- v3 readback: 28 bins x 256 ch -> NCHW, NT float4 stores
        #pragma unroll
        for (int k = 0; k < 7; ++k) {
            const int fidx = k * 256 + tid;               // 0..1791
            const int cl   = fidx / 7;                    // channel 0..255
            const int rem  = fidx - cl * 7;               // bin quad 0..6
            const int slot = ((cl >> 2) + rem) & 63;
            const int e    = cl & 3;
            f32x4 v;
            v[0] = tile[(rem * 4 + 0) * TSF + slot * 4 + e];
            v[1] = tile[(rem * 4 + 1) * TSF + slot * 4 + e];
            v[2] = tile[(rem * 4 + 2) * TSF + slot * 4 + e];
            v[3] = tile[(rem * 4 + 3) * TSF + slot * 4 + e];
            __builtin_nontemporal_store(v,
                (f32x4*)&outr[cl * NB + pass * 28 + rem * 4]);
        }
        __syncthreads();       // protect tile before next pass
    }
}

// ---------------------------------------------------------------- fallback
__global__ __launch_bounds__(256)
void roi_align_nchw(const float* __restrict__ feat,
                    const float* __restrict__ rois,
                    float* __restrict__ out)
{
    const int r  = blockIdx.x;
    const int c0 = blockIdx.y * 128;

    __shared__ int4   s_off[NB];
    __shared__ float4 s_w[NB];
    __shared__ int    s_base;

    const float* roi = rois + r * 5;
    const float x_start = roi[1] * 0.0625f;
    const float y_start = roi[2] * 0.0625f;
    const float roi_w = fmaxf(roi[3] * 0.0625f - x_start, 0.0f);
    const float roi_h = fmaxf(roi[4] * 0.0625f - y_start, 0.0f);
    const float bin_h = roi_h / (float)(AH - 1);
    const float bin_w = roi_w / (float)(AW - 1);

    if (threadIdx.x == 0)
        s_base = ((int)roi[0]) * (Cc * HW);

    for (int i = threadIdx.x; i < NB; i += blockDim.x) {
        const int ph = i / AW;
        const int pw = i - ph * AW;
        float ys = y_start + (float)ph * bin_h;
        float xs = x_start + (float)pw * bin_w;
        ys = fminf(fmaxf(ys, 0.0f), (float)(Hh - 1));
        xs = fminf(fmaxf(xs, 0.0f), (float)(Ww - 1));
        const int y0 = (int)floorf(ys);
        const int x0 = (int)floorf(xs);
        const int y1 = min(y0 + 1, Hh - 1);
        const int x1 = min(x0 + 1, Ww - 1);
        const float wy = ys - (float)y0;
        const float wx = xs - (float)x0;
        s_off[i] = make_int4(y0 * Ww + x0, y0 * Ww + x1,
                             y1 * Ww + x0, y1 * Ww + x1);
        s_w[i]   = make_float4((1.0f - wy) * (1.0f - wx),
                               (1.0f - wy) * wx,
                               wy * (1.0f - wx),
                               wy * wx);
    }
    __syncthreads();

    const int base = s_base;
    float* __restrict__ outr = out + (size_t)r * (Cc * NB);
    const int jend = (c0 + 128) * NB;
    for (int j = c0 * NB + (int)threadIdx.x * 4; j < jend; j += 256 * 4) {
        const int c   = j / NB;
        const int bin = j - c * NB;
        const float* f = feat + base + c * HW;
        float4 v;
        {
            const int4 o = s_off[bin];     const float4 w = s_w[bin];
            v.x = w.x*f[o.x] + w.y*f[o.y] + w.z*f[o.z] + w.w*f[o.w];
        }
        {
            const int4 o = s_off[bin + 1]; const float4 w = s_w[bin + 1];
            v.y = w.x*f[o.x] + w.y*f[o.y] + w.z*f[o.z] + w.w*f[o.w];
        }
        {
            const int4 o = s_off[bin + 2]; const float4 w = s_w[bin + 2];
            v.z = w.x*f[o.x] + w.y*f[o.y] + w.z*f[o.z] + w.w*f[o.w];
        }
        {
            const int4 o = s_off[bin + 3]; const float4 w = s_w[bin + 3];
            v.w = w.x*f[o.x] + w.y*f[o.y] + w.z*f[o.z] + w.w*f[o.w];
        }
        *(float4*)(outr + j) = v;
    }
}

extern "C" void kernel_launch(void* const* d_in, const int* in_sizes, int n_in,
                              void* d_out, int out_size, void* d_ws, size_t ws_size,
                              hipStream_t stream)
{
    const float* feat = (const float*)d_in[0];
    const float* rois = (const float*)d_in[1];
    float*       out  = (float*)d_out;
    const int R = in_sizes[1] / 5;                       // 512

    const size_t need = (size_t)Nn * HW * Cc * sizeof(__half);  // 31.1 MB
    if (ws_size >= need) {
        __half* nhwc = (__half*)d_ws;
        dim3 tg((HW + 63) / 64, Cc / 64, Nn);            // (238, 8, 2)
        nchw_to_nhwc_f16<<<tg, 256, 0, stream>>>(feat, nhwc);
        dim3 mg(R, Cc / CPB);                            // (512, 2)
        roi_align_staged<<<mg, 256, 0, stream>>>(nhwc, rois, out);
    } else {
        dim3 grid(R, Cc / 128);
        roi_align_nchw<<<grid, 256, 0, stream>>>(feat, rois, out);
    }
}